// Round 9
// baseline (121.946 us; speedup 1.0000x reference)
//
#include <hip/hip_runtime.h>

#define NTH 256   // fallback kernel block size
#define NTF 512   // fused kernel block size (8 waves)

using f16x4 = __attribute__((ext_vector_type(4))) _Float16;
using f32x4 = __attribute__((ext_vector_type(4))) float;

// ===========================================================================
// FUSED-PAIR PATH
// State in LDS: S[m][k], m<1024 rows, k<16, row stride 20 halfwords (40 B).
// R5/R7-proven addressing: simple r*20 + slot*4. NO swizzle — both swizzle
// attempts (R6 phi, R8 single-XOR) pushed this 64-VGPR kernel into scratch
// spills (FETCH/WRITE ballooned). Latency is attacked via occupancy instead:
// 512 threads/block, 4 blocks/CU -> 2048 threads/CU (100% cap).
// Row-boundary states packed-flat: value f at (f>>4)*20 + (f&15).
// ===========================================================================

// Prep: fused pair operator A-fragments for mfma_f32_16x16x16f16.
// F[q=(d1,d2,r2)][k] = sum_rj T1[u1,d1,h,rj]*T2[u2,d2,rj,r2]
// 1024 threads: stage both site tensors in LDS, one (lane, frag) per thread.
__global__ void prep_fused(const float* __restrict__ tens, uint2* __restrict__ At)
{
  __shared__ float tl[1024];            // site1 [0:512), site2 [512:1024)
  const int pc   = blockIdx.x;          // 0..71
  const int pair = pc >> 2, combo = pc & 3;
  const int row = pair / 3, jp = pair % 3;
  const int s1 = combo >> 1, s2 = combo & 1;
  const int site1 = row * 6 + jp * 2;
  const int tid = threadIdx.x;          // 0..1023
  tl[tid] = tens[site1 * 512 + tid];    // 2 sites are contiguous (512 apart)
  __syncthreads();

  const int U  = (row == 0) ? 1 : 4;
  const int D  = (row == 5) ? 1 : 4;
  const int H1 = (jp == 0) ? 1 : 4;
  const int R2 = (jp == 2) ? 1 : 4;
  const int lane = tid >> 4, f = tid & 15;      // f fast -> coalesced writes
  const int ql = lane & 15, kgrp = lane >> 4;
  const int type = (row == 0) ? 0 : ((jp == 0) ? 1 : 2);
  const int qb = f >> 2, kb = f & 3;
  const int q = qb * 16 + ql;
  const int d1 = q >> 4, d2 = (q >> 2) & 3, r2 = q & 3;

  f16x4 v;
#pragma unroll
  for (int jj = 0; jj < 4; ++jj) {
    int u1, u2, h, valid = 1;
    if (type == 2)      { u2 = kb; u1 = kgrp; h = jj; }
    else if (type == 1) { valid = (kb == 0); u1 = kgrp; u2 = jj; h = 0; }
    else {
      valid = (kb == 0) && (kgrp == 0);
      u1 = 0; u2 = 0;
      h = (jp == 0) ? 0 : jj;
      if (jp == 0) valid = valid && (jj == 0);
    }
    float acc = 0.f;
    if (valid && d1 < D && d2 < D && r2 < R2 && u1 < U && u2 < U && h < H1) {
#pragma unroll
      for (int rj = 0; rj < 4; ++rj) {
        const float a = tl[u1 * 128 + d1 * 32 + h  * 8 + rj * 2 + s1];
        const float b = tl[512 + u2 * 128 + d2 * 32 + rj * 8 + r2 * 2 + s2];
        acc += a * b;
      }
    }
    v[jj] = (_Float16)acc;
  }
  At[(pc * 64 + lane) * 16 + f] = __builtin_bit_cast(uint2, v);
}

// One fused absorption step (two sites). TYPE: 0=ROW0, 1=START, 2=MID.
// WRMODE: 0=generic (extract u3 to k), 1=row-end packed-flat, 2=final scalar.
// D4: d-legs are dim 4 (rows 0..4); false for row 5.
// 8 waves: wave wv handles tiles t = wv, wv+8, ...
template<int MQ, int LGVR, int LGVC, int TYPE, int WRMODE, bool D4>
__device__ __forceinline__ void fstep(const uint2* __restrict__ At, int pc,
                                      _Float16* __restrict__ S,
                                      float* __restrict__ outp,
                                      int lane, int wv)
{
  const int ml = lane & 15, kg = lane >> 4;
  constexpr int NT  = (MQ + 15) / 16;
  constexpr int NTW = (NT + 7) / 8;
  const uint2* Ap = At + (pc * 64 + lane) * 16;

  f16x4 A[16];
  if (TYPE == 2) {
#pragma unroll
    for (int f = 0; f < (D4 ? 16 : 4); ++f)
      A[f] = __builtin_bit_cast(f16x4, Ap[f]);
  } else {
#pragma unroll
    for (int qb = 0; qb < (D4 ? 4 : 1); ++qb)
      A[qb * 4] = __builtin_bit_cast(f16x4, Ap[qb * 4]);
  }

  // phase 1: gather B-fragments into registers
  f16x4 B[NTW][4];
#pragma unroll
  for (int tt = 0; tt < NTW; ++tt) {
    const int t = wv + 8 * tt;
    if (t < NT) {
      const int m = t * 16 + ml;
      if (TYPE == 2) {
        const int w = m >> LGVR, vr = m & ((1 << LGVR) - 1);
#pragma unroll
        for (int kb = 0; kb < 4; ++kb) {
          const int r0 = (((w << 2) | kb) << LGVR) | vr;
          B[tt][kb] = *(const f16x4*)&S[r0 * 20 + kg * 4];
        }
      } else if (TYPE == 1) {
        const int f0 = ((kg << LGVR) | m) << 2;
        B[tt][0] = *(const f16x4*)&S[(f0 >> 4) * 20 + (f0 & 15)];
      } else {
        B[tt][0] = *(const f16x4*)&S[m * 20 + kg * 4];
      }
    }
  }
  __syncthreads();

  // phase 2: MFMA + in-place write in the consumer's layout
#pragma unroll
  for (int tt = 0; tt < NTW; ++tt) {
    const int t = wv + 8 * tt;
    if (t < NT) {
      const int m = t * 16 + ml;
      f32x4 acc[4];
#pragma unroll
      for (int qb = 0; qb < (D4 ? 4 : 1); ++qb) {
        acc[qb] = (f32x4){0.f, 0.f, 0.f, 0.f};
        if (TYPE == 2) {
#pragma unroll
          for (int kb = 0; kb < 4; ++kb)
            acc[qb] = __builtin_amdgcn_mfma_f32_16x16x16f16(A[qb * 4 + kb],
                                                            B[tt][kb], acc[qb], 0, 0, 0);
        } else {
          acc[qb] = __builtin_amdgcn_mfma_f32_16x16x16f16(A[qb * 4],
                                                          B[tt][0], acc[qb], 0, 0, 0);
        }
      }
      if (m < MQ) {
        if (WRMODE == 2) {
          if (lane == 0) *outp = acc[0][0];
        } else if (WRMODE == 1) {
          // row-end: only r2=0 (reg 0) valid; scatter packed-flat
#pragma unroll
          for (int qb = 0; qb < 4; ++qb) {
            const int wp = (m << 4) | (qb << 2) | kg;
            const int f  = ((wp >> 10) << 10) | ((wp & 255) << 2) | ((wp >> 8) & 3);
            S[(f >> 4) * 20 + (f & 15)] = (_Float16)acc[qb][0];
          }
        } else {
          const int w2 = m >> LGVR, vr2 = m & ((1 << LGVR) - 1);
          const int u3 = vr2 >> LGVC, vc = vr2 & ((1 << LGVC) - 1);
#pragma unroll
          for (int qb = 0; qb < (D4 ? 4 : 1); ++qb) {
            const int wq = D4 ? ((w2 << 4) | (qb << 2) | kg) : w2;
            const int m2 = (wq << LGVC) | vc;
            f16x4 pk = { (_Float16)acc[qb][0], (_Float16)acc[qb][1],
                         (_Float16)acc[qb][2], (_Float16)acc[qb][3] };
            if (D4 || kg == 0)
              *(f16x4*)&S[m2 * 20 + u3 * 4] = pk;
          }
        }
      }
    }
  }
  __syncthreads();
}

__global__ __launch_bounds__(NTF, 8)
void tn_fused(const uint2* __restrict__ At, const int* __restrict__ x,
              float* __restrict__ out)
{
  __shared__ __align__(16) _Float16 S[20480];   // 1024 rows * 20, 40 KB
  const int tid = threadIdx.x, b = blockIdx.x;
  const int lane = tid & 63, wv = tid >> 6;     // 8 waves
  const int* xb = x + b * 36;

  uint4* Z = (uint4*)S;
#pragma unroll
  for (int z = 0; z < 5; ++z) Z[tid + NTF * z] = make_uint4(0, 0, 0, 0);
  __syncthreads();
  if (tid == 0) S[0] = (_Float16)1.0f;
  __syncthreads();

  // row 0 (tiny)
  fstep<1,   0, 0, 0, 0, true >(At, (0 << 2) | (xb[0] << 1) | xb[1], S, nullptr, lane, wv);
  fstep<16,  0, 0, 0, 0, true >(At, (1 << 2) | (xb[2] << 1) | xb[3], S, nullptr, lane, wv);
  fstep<256, 0, 0, 0, 1, true >(At, (2 << 2) | (xb[4] << 1) | xb[5], S, nullptr, lane, wv);
  // rows 1..4
#pragma unroll 1
  for (int r = 1; r <= 4; ++r) {
    const int s0 = r * 6, p0 = r * 3;
    fstep<256, 8, 6, 1, 0, true >(At, ((p0 + 0) << 2) | (xb[s0 + 0] << 1) | xb[s0 + 1], S, nullptr, lane, wv);
    fstep<256, 4, 2, 2, 0, true >(At, ((p0 + 1) << 2) | (xb[s0 + 2] << 1) | xb[s0 + 3], S, nullptr, lane, wv);
    fstep<256, 0, 0, 2, 1, true >(At, ((p0 + 2) << 2) | (xb[s0 + 4] << 1) | xb[s0 + 5], S, nullptr, lane, wv);
  }
  // row 5
  fstep<256, 8, 6, 1, 0, false>(At, (15 << 2) | (xb[30] << 1) | xb[31], S, nullptr, lane, wv);
  fstep<16,  4, 2, 2, 0, false>(At, (16 << 2) | (xb[32] << 1) | xb[33], S, nullptr, lane, wv);
  fstep<1,   0, 0, 2, 2, false>(At, (17 << 2) | (xb[34] << 1) | xb[35], S, out + b, lane, wv);
}

// ===========================================================================
// FALLBACK (ws too small): R3's in-place fp32 LDS kernel (proven).
// ===========================================================================
__device__ __forceinline__ int swz(int f) { return f ^ (((f >> 6) & 7) << 2); }
__device__ __forceinline__ void fma4(float4& a, const float4& v, float s) {
  a.x = fmaf(v.x, s, a.x); a.y = fmaf(v.y, s, a.y);
  a.z = fmaf(v.z, s, a.z); a.w = fmaf(v.w, s, a.w);
}
template<int U, int D, int H, int R>
__device__ __forceinline__ void step_f(const float* __restrict__ tb,
                                       float* __restrict__ buf,
                                       int wcnt, int V, int tid)
{
  constexpr int HU = H * U, DR = D * R;
  if (V >= 4) {
    const int Vq = V >> 2, lvq = 31 - __clz(Vq);
    const int items = wcnt * Vq;
    const bool act = tid < items;
    float4 acc[DR];
    if (act) {
      const int vb = (tid & (Vq - 1)) << 2, w = tid >> lvq;
      const int ib = w * HU * V + vb;
      float4 iv[HU];
#pragma unroll
      for (int hu = 0; hu < HU; ++hu) iv[hu] = *(const float4*)&buf[swz(ib + hu * V)];
#pragma unroll
      for (int q = 0; q < DR; ++q) acc[q] = make_float4(0.f, 0.f, 0.f, 0.f);
#pragma unroll
      for (int hu = 0; hu < HU; ++hu)
#pragma unroll
        for (int q = 0; q < DR / 4; ++q) {
          const float4 t = *(const float4*)&tb[hu * DR + 4 * q];
          fma4(acc[4 * q + 0], iv[hu], t.x); fma4(acc[4 * q + 1], iv[hu], t.y);
          fma4(acc[4 * q + 2], iv[hu], t.z); fma4(acc[4 * q + 3], iv[hu], t.w);
        }
    }
    __syncthreads();
    if (act) {
      const int vb = (tid & (Vq - 1)) << 2, w = tid >> lvq;
      const int ob = w * DR * V + vb;
#pragma unroll
      for (int q = 0; q < DR; ++q) *(float4*)&buf[swz(ob + q * V)] = acc[q];
    }
    __syncthreads();
  } else {
    const int items = wcnt;
    if (DR >= 4) {
      constexpr int NQ = DR / 4;
      constexpr int IPT = (DR == 4) ? 4 : 1;
      float4 acc[IPT][NQ];
#pragma unroll
      for (int it = 0; it < IPT; ++it) {
        const int s = tid + it * NTH;
        if (s < items) {
#pragma unroll
          for (int q = 0; q < NQ; ++q) acc[it][q] = make_float4(0.f, 0.f, 0.f, 0.f);
          const int ib = s * HU;
          if (HU >= 4) {
#pragma unroll
            for (int hq = 0; hq < HU / 4; ++hq) {
              const float4 a = *(const float4*)&buf[swz(ib + 4 * hq)];
              const float av[4] = {a.x, a.y, a.z, a.w};
#pragma unroll
              for (int k = 0; k < 4; ++k)
#pragma unroll
                for (int q = 0; q < NQ; ++q) {
                  const float4 t = *(const float4*)&tb[(4 * hq + k) * DR + 4 * q];
                  fma4(acc[it][q], t, av[k]);
                }
            }
          } else {
            const float a = buf[swz(ib)];
#pragma unroll
            for (int q = 0; q < NQ; ++q) {
              const float4 t = *(const float4*)&tb[4 * q];
              fma4(acc[it][q], t, a);
            }
          }
        }
      }
      __syncthreads();
#pragma unroll
      for (int it = 0; it < IPT; ++it) {
        const int s = tid + it * NTH;
        if (s < items) {
          const int ob = s * DR;
#pragma unroll
          for (int q = 0; q < NQ; ++q) *(float4*)&buf[swz(ob + 4 * q)] = acc[it][q];
        }
      }
      __syncthreads();
    } else {
      float acc = 0.f;
      const bool act = tid < items;
      if (act) {
        const int ib = tid * HU;
#pragma unroll
        for (int hu = 0; hu < HU; ++hu) acc += buf[swz(ib + hu)] * tb[hu];
      }
      __syncthreads();
      if (act) buf[swz(tid)] = acc;
      __syncthreads();
    }
  }
}
template<int U, int D, int H, int R>
__device__ __forceinline__ void step_lds(const float* __restrict__ tens, int sbase,
                                         float* __restrict__ buf, float* __restrict__ sT,
                                         int wcnt, int V, int tid)
{
  constexpr int TSZ = H * U * D * R;
  if (tid < TSZ) {
    int t = tid;
    const int r = t % R; t /= R;
    const int d = t % D; t /= D;
    const int u = t % U; t /= U;
    const int h = t;
    sT[tid] = tens[sbase + u * 128 + d * 32 + h * 8 + r * 2];
  }
  __syncthreads();
  step_f<U, D, H, R>(sT, buf, wcnt, V, tid);
}
__global__ __launch_bounds__(NTH, 2)
void tn_kernel_lds(const float* __restrict__ tensors, const int* __restrict__ x,
                   float* __restrict__ out)
{
  __shared__ __align__(16) float buf[16384];
  __shared__ __align__(16) float sT[256];
  const int b = blockIdx.x, tid = threadIdx.x;
  const int* xb = x + b * 36;
  if (tid == 0) buf[0] = 1.0f;
  __syncthreads();
  int S = 1;
  for (int i = 0; i < 6; ++i) {
    int wcnt = 1, S3 = S;
    for (int j = 0; j < 6; ++j) {
      const int site = i * 6 + j, spin = xb[site];
      const int sbase = site * 512 + spin;
      const int U = (i == 0) ? 1 : 4;
      const int V = (U == 4) ? (S3 >> 2) : S3;
      const int code = ((i != 0) << 3) | ((i != 5) << 2) | ((j != 0) << 1) | ((j != 5) << 0);
      switch (code) {
        case 0b0101: step_lds<1,4,1,4>(tensors, sbase, buf, sT, wcnt, V, tid); break;
        case 0b0111: step_lds<1,4,4,4>(tensors, sbase, buf, sT, wcnt, V, tid); break;
        case 0b0110: step_lds<1,4,4,1>(tensors, sbase, buf, sT, wcnt, V, tid); break;
        case 0b1101: step_lds<4,4,1,4>(tensors, sbase, buf, sT, wcnt, V, tid); break;
        case 0b1111: step_lds<4,4,4,4>(tensors, sbase, buf, sT, wcnt, V, tid); break;
        case 0b1110: step_lds<4,4,4,1>(tensors, sbase, buf, sT, wcnt, V, tid); break;
        case 0b1001: step_lds<4,1,1,4>(tensors, sbase, buf, sT, wcnt, V, tid); break;
        case 0b1011: step_lds<4,1,4,4>(tensors, sbase, buf, sT, wcnt, V, tid); break;
        case 0b1010: step_lds<4,1,4,1>(tensors, sbase, buf, sT, wcnt, V, tid); break;
      }
      const int Dd = (i == 5) ? 1 : 4;
      wcnt *= Dd;
      S3 = V;
    }
    S = wcnt * S3;
  }
  if (tid == 0) out[b] = buf[0];
}

extern "C" void kernel_launch(void* const* d_in, const int* in_sizes, int n_in,
                              void* d_out, int out_size, void* d_ws, size_t ws_size,
                              hipStream_t stream) {
  // setup_inputs order: x (int32, BATCH*36), tensors (f32, 6*6*4*4*4*4*2)
  const int*   x       = (const int*)d_in[0];
  const float* tensors = (const float*)d_in[1];
  float*       out     = (float*)d_out;
  const int batch = in_sizes[0] / 36;
  const size_t need = 72ull * 64 * 16 * 8;   // 589824 B
  if (ws_size >= need && d_ws != nullptr) {
    uint2* At = (uint2*)d_ws;
    prep_fused<<<72, 1024, 0, stream>>>(tensors, At);
    tn_fused<<<batch, NTF, 0, stream>>>(At, x, out);
  } else {
    tn_kernel_lds<<<batch, NTH, 0, stream>>>(tensors, x, out);
  }
}

// Round 10
// 96.941 us; speedup vs baseline: 1.2579x; 1.2579x over previous
//
#include <hip/hip_runtime.h>

#define NTH 256   // fallback kernel block size
#define NTF 512   // fused kernel block size (8 waves)

using f16x4 = __attribute__((ext_vector_type(4))) _Float16;
using f32x4 = __attribute__((ext_vector_type(4))) float;

// ===========================================================================
// FUSED-PAIR PATH
// State in LDS: S[m][k], m<1024 rows, k<16, row stride 20 halfwords (40 B).
// R5/R7-proven addressing: simple r*20 + slot*4. NO swizzle (R6/R8 both
// spilled). 512 threads/block; launch_bounds min-waves=4 (VGPR cap 128) so
// the allocator is NOT squeezed — R9's (512,8) forced a 32-VGPR allocation
// with 36 MB of scratch spill traffic. With natural ~60 VGPR, LDS (40 KB)
// limits to 4 blocks/CU = 2048 threads = 100% occupancy cap.
// Row-boundary states packed-flat: value f at (f>>4)*20 + (f&15).
// ===========================================================================

// Prep: fused pair operator A-fragments for mfma_f32_16x16x16f16.
// F[q=(d1,d2,r2)][k] = sum_rj T1[u1,d1,h,rj]*T2[u2,d2,rj,r2]
// 1024 threads: stage both site tensors in LDS, one (lane, frag) per thread.
__global__ void prep_fused(const float* __restrict__ tens, uint2* __restrict__ At)
{
  __shared__ float tl[1024];            // site1 [0:512), site2 [512:1024)
  const int pc   = blockIdx.x;          // 0..71
  const int pair = pc >> 2, combo = pc & 3;
  const int row = pair / 3, jp = pair % 3;
  const int s1 = combo >> 1, s2 = combo & 1;
  const int site1 = row * 6 + jp * 2;
  const int tid = threadIdx.x;          // 0..1023
  tl[tid] = tens[site1 * 512 + tid];    // 2 sites are contiguous (512 apart)
  __syncthreads();

  const int U  = (row == 0) ? 1 : 4;
  const int D  = (row == 5) ? 1 : 4;
  const int H1 = (jp == 0) ? 1 : 4;
  const int R2 = (jp == 2) ? 1 : 4;
  const int lane = tid >> 4, f = tid & 15;      // f fast -> coalesced writes
  const int ql = lane & 15, kgrp = lane >> 4;
  const int type = (row == 0) ? 0 : ((jp == 0) ? 1 : 2);
  const int qb = f >> 2, kb = f & 3;
  const int q = qb * 16 + ql;
  const int d1 = q >> 4, d2 = (q >> 2) & 3, r2 = q & 3;

  f16x4 v;
#pragma unroll
  for (int jj = 0; jj < 4; ++jj) {
    int u1, u2, h, valid = 1;
    if (type == 2)      { u2 = kb; u1 = kgrp; h = jj; }
    else if (type == 1) { valid = (kb == 0); u1 = kgrp; u2 = jj; h = 0; }
    else {
      valid = (kb == 0) && (kgrp == 0);
      u1 = 0; u2 = 0;
      h = (jp == 0) ? 0 : jj;
      if (jp == 0) valid = valid && (jj == 0);
    }
    float acc = 0.f;
    if (valid && d1 < D && d2 < D && r2 < R2 && u1 < U && u2 < U && h < H1) {
#pragma unroll
      for (int rj = 0; rj < 4; ++rj) {
        const float a = tl[u1 * 128 + d1 * 32 + h  * 8 + rj * 2 + s1];
        const float b = tl[512 + u2 * 128 + d2 * 32 + rj * 8 + r2 * 2 + s2];
        acc += a * b;
      }
    }
    v[jj] = (_Float16)acc;
  }
  At[(pc * 64 + lane) * 16 + f] = __builtin_bit_cast(uint2, v);
}

// One fused absorption step (two sites). TYPE: 0=ROW0, 1=START, 2=MID.
// WRMODE: 0=generic (extract u3 to k), 1=row-end packed-flat, 2=final scalar.
// D4: d-legs are dim 4 (rows 0..4); false for row 5.
// 8 waves: wave wv handles tiles t = wv, wv+8, ...
template<int MQ, int LGVR, int LGVC, int TYPE, int WRMODE, bool D4>
__device__ __forceinline__ void fstep(const uint2* __restrict__ At, int pc,
                                      _Float16* __restrict__ S,
                                      float* __restrict__ outp,
                                      int lane, int wv)
{
  const int ml = lane & 15, kg = lane >> 4;
  constexpr int NT  = (MQ + 15) / 16;
  constexpr int NTW = (NT + 7) / 8;
  const uint2* Ap = At + (pc * 64 + lane) * 16;

  f16x4 A[16];
  if (TYPE == 2) {
#pragma unroll
    for (int f = 0; f < (D4 ? 16 : 4); ++f)
      A[f] = __builtin_bit_cast(f16x4, Ap[f]);
  } else {
#pragma unroll
    for (int qb = 0; qb < (D4 ? 4 : 1); ++qb)
      A[qb * 4] = __builtin_bit_cast(f16x4, Ap[qb * 4]);
  }

  // phase 1: gather B-fragments into registers
  f16x4 B[NTW][4];
#pragma unroll
  for (int tt = 0; tt < NTW; ++tt) {
    const int t = wv + 8 * tt;
    if (t < NT) {
      const int m = t * 16 + ml;
      if (TYPE == 2) {
        const int w = m >> LGVR, vr = m & ((1 << LGVR) - 1);
#pragma unroll
        for (int kb = 0; kb < 4; ++kb) {
          const int r0 = (((w << 2) | kb) << LGVR) | vr;
          B[tt][kb] = *(const f16x4*)&S[r0 * 20 + kg * 4];
        }
      } else if (TYPE == 1) {
        const int f0 = ((kg << LGVR) | m) << 2;
        B[tt][0] = *(const f16x4*)&S[(f0 >> 4) * 20 + (f0 & 15)];
      } else {
        B[tt][0] = *(const f16x4*)&S[m * 20 + kg * 4];
      }
    }
  }
  __syncthreads();

  // phase 2: MFMA + in-place write in the consumer's layout
#pragma unroll
  for (int tt = 0; tt < NTW; ++tt) {
    const int t = wv + 8 * tt;
    if (t < NT) {
      const int m = t * 16 + ml;
      f32x4 acc[4];
#pragma unroll
      for (int qb = 0; qb < (D4 ? 4 : 1); ++qb) {
        acc[qb] = (f32x4){0.f, 0.f, 0.f, 0.f};
        if (TYPE == 2) {
#pragma unroll
          for (int kb = 0; kb < 4; ++kb)
            acc[qb] = __builtin_amdgcn_mfma_f32_16x16x16f16(A[qb * 4 + kb],
                                                            B[tt][kb], acc[qb], 0, 0, 0);
        } else {
          acc[qb] = __builtin_amdgcn_mfma_f32_16x16x16f16(A[qb * 4],
                                                          B[tt][0], acc[qb], 0, 0, 0);
        }
      }
      if (m < MQ) {
        if (WRMODE == 2) {
          if (lane == 0) *outp = acc[0][0];
        } else if (WRMODE == 1) {
          // row-end: only r2=0 (reg 0) valid; scatter packed-flat
#pragma unroll
          for (int qb = 0; qb < 4; ++qb) {
            const int wp = (m << 4) | (qb << 2) | kg;
            const int f  = ((wp >> 10) << 10) | ((wp & 255) << 2) | ((wp >> 8) & 3);
            S[(f >> 4) * 20 + (f & 15)] = (_Float16)acc[qb][0];
          }
        } else {
          const int w2 = m >> LGVR, vr2 = m & ((1 << LGVR) - 1);
          const int u3 = vr2 >> LGVC, vc = vr2 & ((1 << LGVC) - 1);
#pragma unroll
          for (int qb = 0; qb < (D4 ? 4 : 1); ++qb) {
            const int wq = D4 ? ((w2 << 4) | (qb << 2) | kg) : w2;
            const int m2 = (wq << LGVC) | vc;
            f16x4 pk = { (_Float16)acc[qb][0], (_Float16)acc[qb][1],
                         (_Float16)acc[qb][2], (_Float16)acc[qb][3] };
            if (D4 || kg == 0)
              *(f16x4*)&S[m2 * 20 + u3 * 4] = pk;
          }
        }
      }
    }
  }
  __syncthreads();
}

__global__ __launch_bounds__(NTF, 4)
void tn_fused(const uint2* __restrict__ At, const int* __restrict__ x,
              float* __restrict__ out)
{
  __shared__ __align__(16) _Float16 S[20480];   // 1024 rows * 20, 40 KB
  const int tid = threadIdx.x, b = blockIdx.x;
  const int lane = tid & 63, wv = tid >> 6;     // 8 waves
  const int* xb = x + b * 36;

  uint4* Z = (uint4*)S;
#pragma unroll
  for (int z = 0; z < 5; ++z) Z[tid + NTF * z] = make_uint4(0, 0, 0, 0);
  __syncthreads();
  if (tid == 0) S[0] = (_Float16)1.0f;
  __syncthreads();

  // row 0 (tiny)
  fstep<1,   0, 0, 0, 0, true >(At, (0 << 2) | (xb[0] << 1) | xb[1], S, nullptr, lane, wv);
  fstep<16,  0, 0, 0, 0, true >(At, (1 << 2) | (xb[2] << 1) | xb[3], S, nullptr, lane, wv);
  fstep<256, 0, 0, 0, 1, true >(At, (2 << 2) | (xb[4] << 1) | xb[5], S, nullptr, lane, wv);
  // rows 1..4
#pragma unroll 1
  for (int r = 1; r <= 4; ++r) {
    const int s0 = r * 6, p0 = r * 3;
    fstep<256, 8, 6, 1, 0, true >(At, ((p0 + 0) << 2) | (xb[s0 + 0] << 1) | xb[s0 + 1], S, nullptr, lane, wv);
    fstep<256, 4, 2, 2, 0, true >(At, ((p0 + 1) << 2) | (xb[s0 + 2] << 1) | xb[s0 + 3], S, nullptr, lane, wv);
    fstep<256, 0, 0, 2, 1, true >(At, ((p0 + 2) << 2) | (xb[s0 + 4] << 1) | xb[s0 + 5], S, nullptr, lane, wv);
  }
  // row 5
  fstep<256, 8, 6, 1, 0, false>(At, (15 << 2) | (xb[30] << 1) | xb[31], S, nullptr, lane, wv);
  fstep<16,  4, 2, 2, 0, false>(At, (16 << 2) | (xb[32] << 1) | xb[33], S, nullptr, lane, wv);
  fstep<1,   0, 0, 2, 2, false>(At, (17 << 2) | (xb[34] << 1) | xb[35], S, out + b, lane, wv);
}

// ===========================================================================
// FALLBACK (ws too small): R3's in-place fp32 LDS kernel (proven).
// ===========================================================================
__device__ __forceinline__ int swz(int f) { return f ^ (((f >> 6) & 7) << 2); }
__device__ __forceinline__ void fma4(float4& a, const float4& v, float s) {
  a.x = fmaf(v.x, s, a.x); a.y = fmaf(v.y, s, a.y);
  a.z = fmaf(v.z, s, a.z); a.w = fmaf(v.w, s, a.w);
}
template<int U, int D, int H, int R>
__device__ __forceinline__ void step_f(const float* __restrict__ tb,
                                       float* __restrict__ buf,
                                       int wcnt, int V, int tid)
{
  constexpr int HU = H * U, DR = D * R;
  if (V >= 4) {
    const int Vq = V >> 2, lvq = 31 - __clz(Vq);
    const int items = wcnt * Vq;
    const bool act = tid < items;
    float4 acc[DR];
    if (act) {
      const int vb = (tid & (Vq - 1)) << 2, w = tid >> lvq;
      const int ib = w * HU * V + vb;
      float4 iv[HU];
#pragma unroll
      for (int hu = 0; hu < HU; ++hu) iv[hu] = *(const float4*)&buf[swz(ib + hu * V)];
#pragma unroll
      for (int q = 0; q < DR; ++q) acc[q] = make_float4(0.f, 0.f, 0.f, 0.f);
#pragma unroll
      for (int hu = 0; hu < HU; ++hu)
#pragma unroll
        for (int q = 0; q < DR / 4; ++q) {
          const float4 t = *(const float4*)&tb[hu * DR + 4 * q];
          fma4(acc[4 * q + 0], iv[hu], t.x); fma4(acc[4 * q + 1], iv[hu], t.y);
          fma4(acc[4 * q + 2], iv[hu], t.z); fma4(acc[4 * q + 3], iv[hu], t.w);
        }
    }
    __syncthreads();
    if (act) {
      const int vb = (tid & (Vq - 1)) << 2, w = tid >> lvq;
      const int ob = w * DR * V + vb;
#pragma unroll
      for (int q = 0; q < DR; ++q) *(float4*)&buf[swz(ob + q * V)] = acc[q];
    }
    __syncthreads();
  } else {
    const int items = wcnt;
    if (DR >= 4) {
      constexpr int NQ = DR / 4;
      constexpr int IPT = (DR == 4) ? 4 : 1;
      float4 acc[IPT][NQ];
#pragma unroll
      for (int it = 0; it < IPT; ++it) {
        const int s = tid + it * NTH;
        if (s < items) {
#pragma unroll
          for (int q = 0; q < NQ; ++q) acc[it][q] = make_float4(0.f, 0.f, 0.f, 0.f);
          const int ib = s * HU;
          if (HU >= 4) {
#pragma unroll
            for (int hq = 0; hq < HU / 4; ++hq) {
              const float4 a = *(const float4*)&buf[swz(ib + 4 * hq)];
              const float av[4] = {a.x, a.y, a.z, a.w};
#pragma unroll
              for (int k = 0; k < 4; ++k)
#pragma unroll
                for (int q = 0; q < NQ; ++q) {
                  const float4 t = *(const float4*)&tb[(4 * hq + k) * DR + 4 * q];
                  fma4(acc[it][q], t, av[k]);
                }
            }
          } else {
            const float a = buf[swz(ib)];
#pragma unroll
            for (int q = 0; q < NQ; ++q) {
              const float4 t = *(const float4*)&tb[4 * q];
              fma4(acc[it][q], t, a);
            }
          }
        }
      }
      __syncthreads();
#pragma unroll
      for (int it = 0; it < IPT; ++it) {
        const int s = tid + it * NTH;
        if (s < items) {
          const int ob = s * DR;
#pragma unroll
          for (int q = 0; q < NQ; ++q) *(float4*)&buf[swz(ob + 4 * q)] = acc[it][q];
        }
      }
      __syncthreads();
    } else {
      float acc = 0.f;
      const bool act = tid < items;
      if (act) {
        const int ib = tid * HU;
#pragma unroll
        for (int hu = 0; hu < HU; ++hu) acc += buf[swz(ib + hu)] * tb[hu];
      }
      __syncthreads();
      if (act) buf[swz(tid)] = acc;
      __syncthreads();
    }
  }
}
template<int U, int D, int H, int R>
__device__ __forceinline__ void step_lds(const float* __restrict__ tens, int sbase,
                                         float* __restrict__ buf, float* __restrict__ sT,
                                         int wcnt, int V, int tid)
{
  constexpr int TSZ = H * U * D * R;
  if (tid < TSZ) {
    int t = tid;
    const int r = t % R; t /= R;
    const int d = t % D; t /= D;
    const int u = t % U; t /= U;
    const int h = t;
    sT[tid] = tens[sbase + u * 128 + d * 32 + h * 8 + r * 2];
  }
  __syncthreads();
  step_f<U, D, H, R>(sT, buf, wcnt, V, tid);
}
__global__ __launch_bounds__(NTH, 2)
void tn_kernel_lds(const float* __restrict__ tensors, const int* __restrict__ x,
                   float* __restrict__ out)
{
  __shared__ __align__(16) float buf[16384];
  __shared__ __align__(16) float sT[256];
  const int b = blockIdx.x, tid = threadIdx.x;
  const int* xb = x + b * 36;
  if (tid == 0) buf[0] = 1.0f;
  __syncthreads();
  int S = 1;
  for (int i = 0; i < 6; ++i) {
    int wcnt = 1, S3 = S;
    for (int j = 0; j < 6; ++j) {
      const int site = i * 6 + j, spin = xb[site];
      const int sbase = site * 512 + spin;
      const int U = (i == 0) ? 1 : 4;
      const int V = (U == 4) ? (S3 >> 2) : S3;
      const int code = ((i != 0) << 3) | ((i != 5) << 2) | ((j != 0) << 1) | ((j != 5) << 0);
      switch (code) {
        case 0b0101: step_lds<1,4,1,4>(tensors, sbase, buf, sT, wcnt, V, tid); break;
        case 0b0111: step_lds<1,4,4,4>(tensors, sbase, buf, sT, wcnt, V, tid); break;
        case 0b0110: step_lds<1,4,4,1>(tensors, sbase, buf, sT, wcnt, V, tid); break;
        case 0b1101: step_lds<4,4,1,4>(tensors, sbase, buf, sT, wcnt, V, tid); break;
        case 0b1111: step_lds<4,4,4,4>(tensors, sbase, buf, sT, wcnt, V, tid); break;
        case 0b1110: step_lds<4,4,4,1>(tensors, sbase, buf, sT, wcnt, V, tid); break;
        case 0b1001: step_lds<4,1,1,4>(tensors, sbase, buf, sT, wcnt, V, tid); break;
        case 0b1011: step_lds<4,1,4,4>(tensors, sbase, buf, sT, wcnt, V, tid); break;
        case 0b1010: step_lds<4,1,4,1>(tensors, sbase, buf, sT, wcnt, V, tid); break;
      }
      const int Dd = (i == 5) ? 1 : 4;
      wcnt *= Dd;
      S3 = V;
    }
    S = wcnt * S3;
  }
  if (tid == 0) out[b] = buf[0];
}

extern "C" void kernel_launch(void* const* d_in, const int* in_sizes, int n_in,
                              void* d_out, int out_size, void* d_ws, size_t ws_size,
                              hipStream_t stream) {
  // setup_inputs order: x (int32, BATCH*36), tensors (f32, 6*6*4*4*4*4*2)
  const int*   x       = (const int*)d_in[0];
  const float* tensors = (const float*)d_in[1];
  float*       out     = (float*)d_out;
  const int batch = in_sizes[0] / 36;
  const size_t need = 72ull * 64 * 16 * 8;   // 589824 B
  if (ws_size >= need && d_ws != nullptr) {
    uint2* At = (uint2*)d_ws;
    prep_fused<<<72, 1024, 0, stream>>>(tensors, At);
    tn_fused<<<batch, NTF, 0, stream>>>(At, x, out);
  } else {
    tn_kernel_lds<<<batch, NTH, 0, stream>>>(tensors, x, out);
  }
}

// Round 11
// 56.891 us; speedup vs baseline: 2.1435x; 1.7040x over previous
//
#include <hip/hip_runtime.h>

#define NTH 256

using f16x4 = __attribute__((ext_vector_type(4))) _Float16;
using f32x4 = __attribute__((ext_vector_type(4))) float;

// ===========================================================================
// FUSED-PAIR PATH (R7 champion configuration — final).
// State in LDS: S[m][k], m<1024 rows, k<16, row stride 20 halfwords (40 B).
// Addressing: simple r*20 + slot*4. NO swizzle, 256 threads, 4 waves.
// Session evidence for why this exact shape:
//  - R6 phi-swizzle / R8 XOR-swizzle: scratch spills (FETCH 2.5->82/7.5MB) — this
//    kernel sits at the VGPR cliff; any per-access address arithmetic spills.
//  - R9 (512thr, LB(512,8)): 32-VGPR forced allocation, 36MB spill traffic.
//  - R10 (512thr, LB(512,4)): clean codegen but 92us — halved per-wave ILP.
//  - b64 patterns are at the wave64 bank floor; remaining conflicts live in
//    the packed-flat row-boundary interface whose writer/reader vary disjoint
//    bits — not fixable by cheap bijection (6-bit bank window < 10 bits).
// Row-boundary states packed-flat: value f at (f>>4)*20 + (f&15).
// ===========================================================================

// Prep: fused pair operator A-fragments for mfma_f32_16x16x16f16.
// F[q=(d1,d2,r2)][k] = sum_rj T1[u1,d1,h,rj]*T2[u2,d2,rj,r2]
// 1024 threads: stage both site tensors in LDS, one (lane, frag) per thread.
__global__ void prep_fused(const float* __restrict__ tens, uint2* __restrict__ At)
{
  __shared__ float tl[1024];            // site1 [0:512), site2 [512:1024)
  const int pc   = blockIdx.x;          // 0..71
  const int pair = pc >> 2, combo = pc & 3;
  const int row = pair / 3, jp = pair % 3;
  const int s1 = combo >> 1, s2 = combo & 1;
  const int site1 = row * 6 + jp * 2;
  const int tid = threadIdx.x;          // 0..1023
  tl[tid] = tens[site1 * 512 + tid];    // 2 sites are contiguous (512 apart)
  __syncthreads();

  const int U  = (row == 0) ? 1 : 4;
  const int D  = (row == 5) ? 1 : 4;
  const int H1 = (jp == 0) ? 1 : 4;
  const int R2 = (jp == 2) ? 1 : 4;
  const int lane = tid >> 4, f = tid & 15;      // f fast -> coalesced writes
  const int ql = lane & 15, kgrp = lane >> 4;
  const int type = (row == 0) ? 0 : ((jp == 0) ? 1 : 2);
  const int qb = f >> 2, kb = f & 3;
  const int q = qb * 16 + ql;
  const int d1 = q >> 4, d2 = (q >> 2) & 3, r2 = q & 3;

  f16x4 v;
#pragma unroll
  for (int jj = 0; jj < 4; ++jj) {
    int u1, u2, h, valid = 1;
    if (type == 2)      { u2 = kb; u1 = kgrp; h = jj; }
    else if (type == 1) { valid = (kb == 0); u1 = kgrp; u2 = jj; h = 0; }
    else {
      valid = (kb == 0) && (kgrp == 0);
      u1 = 0; u2 = 0;
      h = (jp == 0) ? 0 : jj;
      if (jp == 0) valid = valid && (jj == 0);
    }
    float acc = 0.f;
    if (valid && d1 < D && d2 < D && r2 < R2 && u1 < U && u2 < U && h < H1) {
#pragma unroll
      for (int rj = 0; rj < 4; ++rj) {
        const float a = tl[u1 * 128 + d1 * 32 + h  * 8 + rj * 2 + s1];
        const float b = tl[512 + u2 * 128 + d2 * 32 + rj * 8 + r2 * 2 + s2];
        acc += a * b;
      }
    }
    v[jj] = (_Float16)acc;
  }
  At[(pc * 64 + lane) * 16 + f] = __builtin_bit_cast(uint2, v);
}

// One fused absorption step (two sites). TYPE: 0=ROW0, 1=START, 2=MID.
// WRMODE: 0=generic (extract u3 to k), 1=row-end packed-flat, 2=final scalar.
// D4: d-legs are dim 4 (rows 0..4); false for row 5.
template<int MQ, int LGVR, int LGVC, int TYPE, int WRMODE, bool D4>
__device__ __forceinline__ void fstep(const uint2* __restrict__ At, int pc,
                                      _Float16* __restrict__ S,
                                      float* __restrict__ outp,
                                      int lane, int wv)
{
  const int ml = lane & 15, kg = lane >> 4;
  constexpr int NT  = (MQ + 15) / 16;
  constexpr int NTW = (NT + 3) / 4;
  const uint2* Ap = At + (pc * 64 + lane) * 16;

  f16x4 A[16];
  if (TYPE == 2) {
#pragma unroll
    for (int f = 0; f < (D4 ? 16 : 4); ++f)
      A[f] = __builtin_bit_cast(f16x4, Ap[f]);
  } else {
#pragma unroll
    for (int qb = 0; qb < (D4 ? 4 : 1); ++qb)
      A[qb * 4] = __builtin_bit_cast(f16x4, Ap[qb * 4]);
  }

  // phase 1: gather B-fragments into registers
  f16x4 B[NTW][4];
#pragma unroll
  for (int tt = 0; tt < NTW; ++tt) {
    const int t = wv + 4 * tt;
    if (t < NT) {
      const int m = t * 16 + ml;
      if (TYPE == 2) {
        const int w = m >> LGVR, vr = m & ((1 << LGVR) - 1);
#pragma unroll
        for (int kb = 0; kb < 4; ++kb) {
          const int r0 = (((w << 2) | kb) << LGVR) | vr;
          B[tt][kb] = *(const f16x4*)&S[r0 * 20 + kg * 4];
        }
      } else if (TYPE == 1) {
        const int f0 = ((kg << LGVR) | m) << 2;
        B[tt][0] = *(const f16x4*)&S[(f0 >> 4) * 20 + (f0 & 15)];
      } else {
        B[tt][0] = *(const f16x4*)&S[m * 20 + kg * 4];
      }
    }
  }
  __syncthreads();

  // phase 2: MFMA + in-place write in the consumer's layout
#pragma unroll
  for (int tt = 0; tt < NTW; ++tt) {
    const int t = wv + 4 * tt;
    if (t < NT) {
      const int m = t * 16 + ml;
      f32x4 acc[4];
#pragma unroll
      for (int qb = 0; qb < (D4 ? 4 : 1); ++qb) {
        acc[qb] = (f32x4){0.f, 0.f, 0.f, 0.f};
        if (TYPE == 2) {
#pragma unroll
          for (int kb = 0; kb < 4; ++kb)
            acc[qb] = __builtin_amdgcn_mfma_f32_16x16x16f16(A[qb * 4 + kb],
                                                            B[tt][kb], acc[qb], 0, 0, 0);
        } else {
          acc[qb] = __builtin_amdgcn_mfma_f32_16x16x16f16(A[qb * 4],
                                                          B[tt][0], acc[qb], 0, 0, 0);
        }
      }
      if (m < MQ) {
        if (WRMODE == 2) {
          if (lane == 0) *outp = acc[0][0];
        } else if (WRMODE == 1) {
          // row-end: only r2=0 (reg 0) valid; scatter packed-flat
#pragma unroll
          for (int qb = 0; qb < 4; ++qb) {
            const int wp = (m << 4) | (qb << 2) | kg;
            const int f  = ((wp >> 10) << 10) | ((wp & 255) << 2) | ((wp >> 8) & 3);
            S[(f >> 4) * 20 + (f & 15)] = (_Float16)acc[qb][0];
          }
        } else {
          const int w2 = m >> LGVR, vr2 = m & ((1 << LGVR) - 1);
          const int u3 = vr2 >> LGVC, vc = vr2 & ((1 << LGVC) - 1);
#pragma unroll
          for (int qb = 0; qb < (D4 ? 4 : 1); ++qb) {
            const int wq = D4 ? ((w2 << 4) | (qb << 2) | kg) : w2;
            const int m2 = (wq << LGVC) | vc;
            f16x4 pk = { (_Float16)acc[qb][0], (_Float16)acc[qb][1],
                         (_Float16)acc[qb][2], (_Float16)acc[qb][3] };
            if (D4 || kg == 0)
              *(f16x4*)&S[m2 * 20 + u3 * 4] = pk;
          }
        }
      }
    }
  }
  __syncthreads();
}

__global__ __launch_bounds__(NTH, 4)
void tn_fused(const uint2* __restrict__ At, const int* __restrict__ x,
              float* __restrict__ out)
{
  __shared__ __align__(16) _Float16 S[20480];   // 1024 rows * 20, 40 KB
  const int tid = threadIdx.x, b = blockIdx.x;
  const int lane = tid & 63, wv = tid >> 6;
  const int* xb = x + b * 36;

  uint4* Z = (uint4*)S;
#pragma unroll
  for (int z = 0; z < 10; ++z) Z[tid + NTH * z] = make_uint4(0, 0, 0, 0);
  __syncthreads();
  if (tid == 0) S[0] = (_Float16)1.0f;
  __syncthreads();

  // row 0 (tiny)
  fstep<1,   0, 0, 0, 0, true >(At, (0 << 2) | (xb[0] << 1) | xb[1], S, nullptr, lane, wv);
  fstep<16,  0, 0, 0, 0, true >(At, (1 << 2) | (xb[2] << 1) | xb[3], S, nullptr, lane, wv);
  fstep<256, 0, 0, 0, 1, true >(At, (2 << 2) | (xb[4] << 1) | xb[5], S, nullptr, lane, wv);
  // rows 1..4
#pragma unroll 1
  for (int r = 1; r <= 4; ++r) {
    const int s0 = r * 6, p0 = r * 3;
    fstep<256, 8, 6, 1, 0, true >(At, ((p0 + 0) << 2) | (xb[s0 + 0] << 1) | xb[s0 + 1], S, nullptr, lane, wv);
    fstep<256, 4, 2, 2, 0, true >(At, ((p0 + 1) << 2) | (xb[s0 + 2] << 1) | xb[s0 + 3], S, nullptr, lane, wv);
    fstep<256, 0, 0, 2, 1, true >(At, ((p0 + 2) << 2) | (xb[s0 + 4] << 1) | xb[s0 + 5], S, nullptr, lane, wv);
  }
  // row 5
  fstep<256, 8, 6, 1, 0, false>(At, (15 << 2) | (xb[30] << 1) | xb[31], S, nullptr, lane, wv);
  fstep<16,  4, 2, 2, 0, false>(At, (16 << 2) | (xb[32] << 1) | xb[33], S, nullptr, lane, wv);
  fstep<1,   0, 0, 2, 2, false>(At, (17 << 2) | (xb[34] << 1) | xb[35], S, out + b, lane, wv);
}

// ===========================================================================
// FALLBACK (ws too small): R3's in-place fp32 LDS kernel (proven).
// ===========================================================================
__device__ __forceinline__ int swz(int f) { return f ^ (((f >> 6) & 7) << 2); }
__device__ __forceinline__ void fma4(float4& a, const float4& v, float s) {
  a.x = fmaf(v.x, s, a.x); a.y = fmaf(v.y, s, a.y);
  a.z = fmaf(v.z, s, a.z); a.w = fmaf(v.w, s, a.w);
}
template<int U, int D, int H, int R>
__device__ __forceinline__ void step_f(const float* __restrict__ tb,
                                       float* __restrict__ buf,
                                       int wcnt, int V, int tid)
{
  constexpr int HU = H * U, DR = D * R;
  if (V >= 4) {
    const int Vq = V >> 2, lvq = 31 - __clz(Vq);
    const int items = wcnt * Vq;
    const bool act = tid < items;
    float4 acc[DR];
    if (act) {
      const int vb = (tid & (Vq - 1)) << 2, w = tid >> lvq;
      const int ib = w * HU * V + vb;
      float4 iv[HU];
#pragma unroll
      for (int hu = 0; hu < HU; ++hu) iv[hu] = *(const float4*)&buf[swz(ib + hu * V)];
#pragma unroll
      for (int q = 0; q < DR; ++q) acc[q] = make_float4(0.f, 0.f, 0.f, 0.f);
#pragma unroll
      for (int hu = 0; hu < HU; ++hu)
#pragma unroll
        for (int q = 0; q < DR / 4; ++q) {
          const float4 t = *(const float4*)&tb[hu * DR + 4 * q];
          fma4(acc[4 * q + 0], iv[hu], t.x); fma4(acc[4 * q + 1], iv[hu], t.y);
          fma4(acc[4 * q + 2], iv[hu], t.z); fma4(acc[4 * q + 3], iv[hu], t.w);
        }
    }
    __syncthreads();
    if (act) {
      const int vb = (tid & (Vq - 1)) << 2, w = tid >> lvq;
      const int ob = w * DR * V + vb;
#pragma unroll
      for (int q = 0; q < DR; ++q) *(float4*)&buf[swz(ob + q * V)] = acc[q];
    }
    __syncthreads();
  } else {
    const int items = wcnt;
    if (DR >= 4) {
      constexpr int NQ = DR / 4;
      constexpr int IPT = (DR == 4) ? 4 : 1;
      float4 acc[IPT][NQ];
#pragma unroll
      for (int it = 0; it < IPT; ++it) {
        const int s = tid + it * NTH;
        if (s < items) {
#pragma unroll
          for (int q = 0; q < NQ; ++q) acc[it][q] = make_float4(0.f, 0.f, 0.f, 0.f);
          const int ib = s * HU;
          if (HU >= 4) {
#pragma unroll
            for (int hq = 0; hq < HU / 4; ++hq) {
              const float4 a = *(const float4*)&buf[swz(ib + 4 * hq)];
              const float av[4] = {a.x, a.y, a.z, a.w};
#pragma unroll
              for (int k = 0; k < 4; ++k)
#pragma unroll
                for (int q = 0; q < NQ; ++q) {
                  const float4 t = *(const float4*)&tb[(4 * hq + k) * DR + 4 * q];
                  fma4(acc[it][q], t, av[k]);
                }
            }
          } else {
            const float a = buf[swz(ib)];
#pragma unroll
            for (int q = 0; q < NQ; ++q) {
              const float4 t = *(const float4*)&tb[4 * q];
              fma4(acc[it][q], t, a);
            }
          }
        }
      }
      __syncthreads();
#pragma unroll
      for (int it = 0; it < IPT; ++it) {
        const int s = tid + it * NTH;
        if (s < items) {
          const int ob = s * DR;
#pragma unroll
          for (int q = 0; q < NQ; ++q) *(float4*)&buf[swz(ob + 4 * q)] = acc[it][q];
        }
      }
      __syncthreads();
    } else {
      float acc = 0.f;
      const bool act = tid < items;
      if (act) {
        const int ib = tid * HU;
#pragma unroll
        for (int hu = 0; hu < HU; ++hu) acc += buf[swz(ib + hu)] * tb[hu];
      }
      __syncthreads();
      if (act) buf[swz(tid)] = acc;
      __syncthreads();
    }
  }
}
template<int U, int D, int H, int R>
__device__ __forceinline__ void step_lds(const float* __restrict__ tens, int sbase,
                                         float* __restrict__ buf, float* __restrict__ sT,
                                         int wcnt, int V, int tid)
{
  constexpr int TSZ = H * U * D * R;
  if (tid < TSZ) {
    int t = tid;
    const int r = t % R; t /= R;
    const int d = t % D; t /= D;
    const int u = t % U; t /= U;
    const int h = t;
    sT[tid] = tens[sbase + u * 128 + d * 32 + h * 8 + r * 2];
  }
  __syncthreads();
  step_f<U, D, H, R>(sT, buf, wcnt, V, tid);
}
__global__ __launch_bounds__(NTH, 2)
void tn_kernel_lds(const float* __restrict__ tensors, const int* __restrict__ x,
                   float* __restrict__ out)
{
  __shared__ __align__(16) float buf[16384];
  __shared__ __align__(16) float sT[256];
  const int b = blockIdx.x, tid = threadIdx.x;
  const int* xb = x + b * 36;
  if (tid == 0) buf[0] = 1.0f;
  __syncthreads();
  int S = 1;
  for (int i = 0; i < 6; ++i) {
    int wcnt = 1, S3 = S;
    for (int j = 0; j < 6; ++j) {
      const int site = i * 6 + j, spin = xb[site];
      const int sbase = site * 512 + spin;
      const int U = (i == 0) ? 1 : 4;
      const int V = (U == 4) ? (S3 >> 2) : S3;
      const int code = ((i != 0) << 3) | ((i != 5) << 2) | ((j != 0) << 1) | ((j != 5) << 0);
      switch (code) {
        case 0b0101: step_lds<1,4,1,4>(tensors, sbase, buf, sT, wcnt, V, tid); break;
        case 0b0111: step_lds<1,4,4,4>(tensors, sbase, buf, sT, wcnt, V, tid); break;
        case 0b0110: step_lds<1,4,4,1>(tensors, sbase, buf, sT, wcnt, V, tid); break;
        case 0b1101: step_lds<4,4,1,4>(tensors, sbase, buf, sT, wcnt, V, tid); break;
        case 0b1111: step_lds<4,4,4,4>(tensors, sbase, buf, sT, wcnt, V, tid); break;
        case 0b1110: step_lds<4,4,4,1>(tensors, sbase, buf, sT, wcnt, V, tid); break;
        case 0b1001: step_lds<4,1,1,4>(tensors, sbase, buf, sT, wcnt, V, tid); break;
        case 0b1011: step_lds<4,1,4,4>(tensors, sbase, buf, sT, wcnt, V, tid); break;
        case 0b1010: step_lds<4,1,4,1>(tensors, sbase, buf, sT, wcnt, V, tid); break;
      }
      const int Dd = (i == 5) ? 1 : 4;
      wcnt *= Dd;
      S3 = V;
    }
    S = wcnt * S3;
  }
  if (tid == 0) out[b] = buf[0];
}

extern "C" void kernel_launch(void* const* d_in, const int* in_sizes, int n_in,
                              void* d_out, int out_size, void* d_ws, size_t ws_size,
                              hipStream_t stream) {
  // setup_inputs order: x (int32, BATCH*36), tensors (f32, 6*6*4*4*4*4*2)
  const int*   x       = (const int*)d_in[0];
  const float* tensors = (const float*)d_in[1];
  float*       out     = (float*)d_out;
  const int batch = in_sizes[0] / 36;
  const size_t need = 72ull * 64 * 16 * 8;   // 589824 B
  if (ws_size >= need && d_ws != nullptr) {
    uint2* At = (uint2*)d_ws;
    prep_fused<<<72, 1024, 0, stream>>>(tensors, At);
    tn_fused<<<batch, NTH, 0, stream>>>(At, x, out);
  } else {
    tn_kernel_lds<<<batch, NTH, 0, stream>>>(tensors, x, out);
  }
}

// Round 12
// 56.379 us; speedup vs baseline: 2.1630x; 1.0091x over previous
//
#include <hip/hip_runtime.h>

#define NTH 256

using f16x4 = __attribute__((ext_vector_type(4))) _Float16;
using f32x4 = __attribute__((ext_vector_type(4))) float;

// ===========================================================================
// FUSED-PAIR PATH (R7 champion + T5 setprio around MFMA clusters).
// State in LDS: S[m][k], m<1024 rows, k<16, row stride 20 halfwords (40 B).
// Addressing: simple r*20 + slot*4. NO swizzle, 256 threads, 4 waves.
// Session evidence for this shape: R6/R8 swizzles + R9 launch-bounds cap all
// spilled (VGPR cliff); R10 512-thr clean but -ILP; stride-20 is the bank
// floor among 8B-aligned strides; inter-stage permutation is cross-wave so
// state must transit LDS. T5 rationale: 4 independent blocks/CU at
// uncorrelated phases -> MFMA-priority hint can keep matrix pipe fed
// (attn-like topology, +4-7% there; zero VGPR impact).
// Row-boundary states packed-flat: value f at (f>>4)*20 + (f&15).
// ===========================================================================

// Prep: fused pair operator A-fragments for mfma_f32_16x16x16f16.
// F[q=(d1,d2,r2)][k] = sum_rj T1[u1,d1,h,rj]*T2[u2,d2,rj,r2]
// 1024 threads: stage both site tensors in LDS, one (lane, frag) per thread.
__global__ void prep_fused(const float* __restrict__ tens, uint2* __restrict__ At)
{
  __shared__ float tl[1024];            // site1 [0:512), site2 [512:1024)
  const int pc   = blockIdx.x;          // 0..71
  const int pair = pc >> 2, combo = pc & 3;
  const int row = pair / 3, jp = pair % 3;
  const int s1 = combo >> 1, s2 = combo & 1;
  const int site1 = row * 6 + jp * 2;
  const int tid = threadIdx.x;          // 0..1023
  tl[tid] = tens[site1 * 512 + tid];    // 2 sites are contiguous (512 apart)
  __syncthreads();

  const int U  = (row == 0) ? 1 : 4;
  const int D  = (row == 5) ? 1 : 4;
  const int H1 = (jp == 0) ? 1 : 4;
  const int R2 = (jp == 2) ? 1 : 4;
  const int lane = tid >> 4, f = tid & 15;      // f fast -> coalesced writes
  const int ql = lane & 15, kgrp = lane >> 4;
  const int type = (row == 0) ? 0 : ((jp == 0) ? 1 : 2);
  const int qb = f >> 2, kb = f & 3;
  const int q = qb * 16 + ql;
  const int d1 = q >> 4, d2 = (q >> 2) & 3, r2 = q & 3;

  f16x4 v;
#pragma unroll
  for (int jj = 0; jj < 4; ++jj) {
    int u1, u2, h, valid = 1;
    if (type == 2)      { u2 = kb; u1 = kgrp; h = jj; }
    else if (type == 1) { valid = (kb == 0); u1 = kgrp; u2 = jj; h = 0; }
    else {
      valid = (kb == 0) && (kgrp == 0);
      u1 = 0; u2 = 0;
      h = (jp == 0) ? 0 : jj;
      if (jp == 0) valid = valid && (jj == 0);
    }
    float acc = 0.f;
    if (valid && d1 < D && d2 < D && r2 < R2 && u1 < U && u2 < U && h < H1) {
#pragma unroll
      for (int rj = 0; rj < 4; ++rj) {
        const float a = tl[u1 * 128 + d1 * 32 + h  * 8 + rj * 2 + s1];
        const float b = tl[512 + u2 * 128 + d2 * 32 + rj * 8 + r2 * 2 + s2];
        acc += a * b;
      }
    }
    v[jj] = (_Float16)acc;
  }
  At[(pc * 64 + lane) * 16 + f] = __builtin_bit_cast(uint2, v);
}

// One fused absorption step (two sites). TYPE: 0=ROW0, 1=START, 2=MID.
// WRMODE: 0=generic (extract u3 to k), 1=row-end packed-flat, 2=final scalar.
// D4: d-legs are dim 4 (rows 0..4); false for row 5.
template<int MQ, int LGVR, int LGVC, int TYPE, int WRMODE, bool D4>
__device__ __forceinline__ void fstep(const uint2* __restrict__ At, int pc,
                                      _Float16* __restrict__ S,
                                      float* __restrict__ outp,
                                      int lane, int wv)
{
  const int ml = lane & 15, kg = lane >> 4;
  constexpr int NT  = (MQ + 15) / 16;
  constexpr int NTW = (NT + 3) / 4;
  const uint2* Ap = At + (pc * 64 + lane) * 16;

  f16x4 A[16];
  if (TYPE == 2) {
#pragma unroll
    for (int f = 0; f < (D4 ? 16 : 4); ++f)
      A[f] = __builtin_bit_cast(f16x4, Ap[f]);
  } else {
#pragma unroll
    for (int qb = 0; qb < (D4 ? 4 : 1); ++qb)
      A[qb * 4] = __builtin_bit_cast(f16x4, Ap[qb * 4]);
  }

  // phase 1: gather B-fragments into registers
  f16x4 B[NTW][4];
#pragma unroll
  for (int tt = 0; tt < NTW; ++tt) {
    const int t = wv + 4 * tt;
    if (t < NT) {
      const int m = t * 16 + ml;
      if (TYPE == 2) {
        const int w = m >> LGVR, vr = m & ((1 << LGVR) - 1);
#pragma unroll
        for (int kb = 0; kb < 4; ++kb) {
          const int r0 = (((w << 2) | kb) << LGVR) | vr;
          B[tt][kb] = *(const f16x4*)&S[r0 * 20 + kg * 4];
        }
      } else if (TYPE == 1) {
        const int f0 = ((kg << LGVR) | m) << 2;
        B[tt][0] = *(const f16x4*)&S[(f0 >> 4) * 20 + (f0 & 15)];
      } else {
        B[tt][0] = *(const f16x4*)&S[m * 20 + kg * 4];
      }
    }
  }
  __syncthreads();

  // phase 2: MFMA (prio-boosted, register-only) + in-place write
#pragma unroll
  for (int tt = 0; tt < NTW; ++tt) {
    const int t = wv + 4 * tt;
    if (t < NT) {
      const int m = t * 16 + ml;
      f32x4 acc[4];
      __builtin_amdgcn_s_setprio(1);
#pragma unroll
      for (int qb = 0; qb < (D4 ? 4 : 1); ++qb) {
        acc[qb] = (f32x4){0.f, 0.f, 0.f, 0.f};
        if (TYPE == 2) {
#pragma unroll
          for (int kb = 0; kb < 4; ++kb)
            acc[qb] = __builtin_amdgcn_mfma_f32_16x16x16f16(A[qb * 4 + kb],
                                                            B[tt][kb], acc[qb], 0, 0, 0);
        } else {
          acc[qb] = __builtin_amdgcn_mfma_f32_16x16x16f16(A[qb * 4],
                                                          B[tt][0], acc[qb], 0, 0, 0);
        }
      }
      __builtin_amdgcn_s_setprio(0);
      if (m < MQ) {
        if (WRMODE == 2) {
          if (lane == 0) *outp = acc[0][0];
        } else if (WRMODE == 1) {
          // row-end: only r2=0 (reg 0) valid; scatter packed-flat
#pragma unroll
          for (int qb = 0; qb < 4; ++qb) {
            const int wp = (m << 4) | (qb << 2) | kg;
            const int f  = ((wp >> 10) << 10) | ((wp & 255) << 2) | ((wp >> 8) & 3);
            S[(f >> 4) * 20 + (f & 15)] = (_Float16)acc[qb][0];
          }
        } else {
          const int w2 = m >> LGVR, vr2 = m & ((1 << LGVR) - 1);
          const int u3 = vr2 >> LGVC, vc = vr2 & ((1 << LGVC) - 1);
#pragma unroll
          for (int qb = 0; qb < (D4 ? 4 : 1); ++qb) {
            const int wq = D4 ? ((w2 << 4) | (qb << 2) | kg) : w2;
            const int m2 = (wq << LGVC) | vc;
            f16x4 pk = { (_Float16)acc[qb][0], (_Float16)acc[qb][1],
                         (_Float16)acc[qb][2], (_Float16)acc[qb][3] };
            if (D4 || kg == 0)
              *(f16x4*)&S[m2 * 20 + u3 * 4] = pk;
          }
        }
      }
    }
  }
  __syncthreads();
}

__global__ __launch_bounds__(NTH, 4)
void tn_fused(const uint2* __restrict__ At, const int* __restrict__ x,
              float* __restrict__ out)
{
  __shared__ __align__(16) _Float16 S[20480];   // 1024 rows * 20, 40 KB
  const int tid = threadIdx.x, b = blockIdx.x;
  const int lane = tid & 63, wv = tid >> 6;
  const int* xb = x + b * 36;

  uint4* Z = (uint4*)S;
#pragma unroll
  for (int z = 0; z < 10; ++z) Z[tid + NTH * z] = make_uint4(0, 0, 0, 0);
  __syncthreads();
  if (tid == 0) S[0] = (_Float16)1.0f;
  __syncthreads();

  // row 0 (tiny)
  fstep<1,   0, 0, 0, 0, true >(At, (0 << 2) | (xb[0] << 1) | xb[1], S, nullptr, lane, wv);
  fstep<16,  0, 0, 0, 0, true >(At, (1 << 2) | (xb[2] << 1) | xb[3], S, nullptr, lane, wv);
  fstep<256, 0, 0, 0, 1, true >(At, (2 << 2) | (xb[4] << 1) | xb[5], S, nullptr, lane, wv);
  // rows 1..4
#pragma unroll 1
  for (int r = 1; r <= 4; ++r) {
    const int s0 = r * 6, p0 = r * 3;
    fstep<256, 8, 6, 1, 0, true >(At, ((p0 + 0) << 2) | (xb[s0 + 0] << 1) | xb[s0 + 1], S, nullptr, lane, wv);
    fstep<256, 4, 2, 2, 0, true >(At, ((p0 + 1) << 2) | (xb[s0 + 2] << 1) | xb[s0 + 3], S, nullptr, lane, wv);
    fstep<256, 0, 0, 2, 1, true >(At, ((p0 + 2) << 2) | (xb[s0 + 4] << 1) | xb[s0 + 5], S, nullptr, lane, wv);
  }
  // row 5
  fstep<256, 8, 6, 1, 0, false>(At, (15 << 2) | (xb[30] << 1) | xb[31], S, nullptr, lane, wv);
  fstep<16,  4, 2, 2, 0, false>(At, (16 << 2) | (xb[32] << 1) | xb[33], S, nullptr, lane, wv);
  fstep<1,   0, 0, 2, 2, false>(At, (17 << 2) | (xb[34] << 1) | xb[35], S, out + b, lane, wv);
}

// ===========================================================================
// FALLBACK (ws too small): R3's in-place fp32 LDS kernel (proven).
// ===========================================================================
__device__ __forceinline__ int swz(int f) { return f ^ (((f >> 6) & 7) << 2); }
__device__ __forceinline__ void fma4(float4& a, const float4& v, float s) {
  a.x = fmaf(v.x, s, a.x); a.y = fmaf(v.y, s, a.y);
  a.z = fmaf(v.z, s, a.z); a.w = fmaf(v.w, s, a.w);
}
template<int U, int D, int H, int R>
__device__ __forceinline__ void step_f(const float* __restrict__ tb,
                                       float* __restrict__ buf,
                                       int wcnt, int V, int tid)
{
  constexpr int HU = H * U, DR = D * R;
  if (V >= 4) {
    const int Vq = V >> 2, lvq = 31 - __clz(Vq);
    const int items = wcnt * Vq;
    const bool act = tid < items;
    float4 acc[DR];
    if (act) {
      const int vb = (tid & (Vq - 1)) << 2, w = tid >> lvq;
      const int ib = w * HU * V + vb;
      float4 iv[HU];
#pragma unroll
      for (int hu = 0; hu < HU; ++hu) iv[hu] = *(const float4*)&buf[swz(ib + hu * V)];
#pragma unroll
      for (int q = 0; q < DR; ++q) acc[q] = make_float4(0.f, 0.f, 0.f, 0.f);
#pragma unroll
      for (int hu = 0; hu < HU; ++hu)
#pragma unroll
        for (int q = 0; q < DR / 4; ++q) {
          const float4 t = *(const float4*)&tb[hu * DR + 4 * q];
          fma4(acc[4 * q + 0], iv[hu], t.x); fma4(acc[4 * q + 1], iv[hu], t.y);
          fma4(acc[4 * q + 2], iv[hu], t.z); fma4(acc[4 * q + 3], iv[hu], t.w);
        }
    }
    __syncthreads();
    if (act) {
      const int vb = (tid & (Vq - 1)) << 2, w = tid >> lvq;
      const int ob = w * DR * V + vb;
#pragma unroll
      for (int q = 0; q < DR; ++q) *(float4*)&buf[swz(ob + q * V)] = acc[q];
    }
    __syncthreads();
  } else {
    const int items = wcnt;
    if (DR >= 4) {
      constexpr int NQ = DR / 4;
      constexpr int IPT = (DR == 4) ? 4 : 1;
      float4 acc[IPT][NQ];
#pragma unroll
      for (int it = 0; it < IPT; ++it) {
        const int s = tid + it * NTH;
        if (s < items) {
#pragma unroll
          for (int q = 0; q < NQ; ++q) acc[it][q] = make_float4(0.f, 0.f, 0.f, 0.f);
          const int ib = s * HU;
          if (HU >= 4) {
#pragma unroll
            for (int hq = 0; hq < HU / 4; ++hq) {
              const float4 a = *(const float4*)&buf[swz(ib + 4 * hq)];
              const float av[4] = {a.x, a.y, a.z, a.w};
#pragma unroll
              for (int k = 0; k < 4; ++k)
#pragma unroll
                for (int q = 0; q < NQ; ++q) {
                  const float4 t = *(const float4*)&tb[(4 * hq + k) * DR + 4 * q];
                  fma4(acc[it][q], t, av[k]);
                }
            }
          } else {
            const float a = buf[swz(ib)];
#pragma unroll
            for (int q = 0; q < NQ; ++q) {
              const float4 t = *(const float4*)&tb[4 * q];
              fma4(acc[it][q], t, a);
            }
          }
        }
      }
      __syncthreads();
#pragma unroll
      for (int it = 0; it < IPT; ++it) {
        const int s = tid + it * NTH;
        if (s < items) {
          const int ob = s * DR;
#pragma unroll
          for (int q = 0; q < NQ; ++q) *(float4*)&buf[swz(ob + 4 * q)] = acc[it][q];
        }
      }
      __syncthreads();
    } else {
      float acc = 0.f;
      const bool act = tid < items;
      if (act) {
        const int ib = tid * HU;
#pragma unroll
        for (int hu = 0; hu < HU; ++hu) acc += buf[swz(ib + hu)] * tb[hu];
      }
      __syncthreads();
      if (act) buf[swz(tid)] = acc;
      __syncthreads();
    }
  }
}
template<int U, int D, int H, int R>
__device__ __forceinline__ void step_lds(const float* __restrict__ tens, int sbase,
                                         float* __restrict__ buf, float* __restrict__ sT,
                                         int wcnt, int V, int tid)
{
  constexpr int TSZ = H * U * D * R;
  if (tid < TSZ) {
    int t = tid;
    const int r = t % R; t /= R;
    const int d = t % D; t /= D;
    const int u = t % U; t /= U;
    const int h = t;
    sT[tid] = tens[sbase + u * 128 + d * 32 + h * 8 + r * 2];
  }
  __syncthreads();
  step_f<U, D, H, R>(sT, buf, wcnt, V, tid);
}
__global__ __launch_bounds__(NTH, 2)
void tn_kernel_lds(const float* __restrict__ tensors, const int* __restrict__ x,
                   float* __restrict__ out)
{
  __shared__ __align__(16) float buf[16384];
  __shared__ __align__(16) float sT[256];
  const int b = blockIdx.x, tid = threadIdx.x;
  const int* xb = x + b * 36;
  if (tid == 0) buf[0] = 1.0f;
  __syncthreads();
  int S = 1;
  for (int i = 0; i < 6; ++i) {
    int wcnt = 1, S3 = S;
    for (int j = 0; j < 6; ++j) {
      const int site = i * 6 + j, spin = xb[site];
      const int sbase = site * 512 + spin;
      const int U = (i == 0) ? 1 : 4;
      const int V = (U == 4) ? (S3 >> 2) : S3;
      const int code = ((i != 0) << 3) | ((i != 5) << 2) | ((j != 0) << 1) | ((j != 5) << 0);
      switch (code) {
        case 0b0101: step_lds<1,4,1,4>(tensors, sbase, buf, sT, wcnt, V, tid); break;
        case 0b0111: step_lds<1,4,4,4>(tensors, sbase, buf, sT, wcnt, V, tid); break;
        case 0b0110: step_lds<1,4,4,1>(tensors, sbase, buf, sT, wcnt, V, tid); break;
        case 0b1101: step_lds<4,4,1,4>(tensors, sbase, buf, sT, wcnt, V, tid); break;
        case 0b1111: step_lds<4,4,4,4>(tensors, sbase, buf, sT, wcnt, V, tid); break;
        case 0b1110: step_lds<4,4,4,1>(tensors, sbase, buf, sT, wcnt, V, tid); break;
        case 0b1001: step_lds<4,1,1,4>(tensors, sbase, buf, sT, wcnt, V, tid); break;
        case 0b1011: step_lds<4,1,4,4>(tensors, sbase, buf, sT, wcnt, V, tid); break;
        case 0b1010: step_lds<4,1,4,1>(tensors, sbase, buf, sT, wcnt, V, tid); break;
      }
      const int Dd = (i == 5) ? 1 : 4;
      wcnt *= Dd;
      S3 = V;
    }
    S = wcnt * S3;
  }
  if (tid == 0) out[b] = buf[0];
}

extern "C" void kernel_launch(void* const* d_in, const int* in_sizes, int n_in,
                              void* d_out, int out_size, void* d_ws, size_t ws_size,
                              hipStream_t stream) {
  // setup_inputs order: x (int32, BATCH*36), tensors (f32, 6*6*4*4*4*4*2)
  const int*   x       = (const int*)d_in[0];
  const float* tensors = (const float*)d_in[1];
  float*       out     = (float*)d_out;
  const int batch = in_sizes[0] / 36;
  const size_t need = 72ull * 64 * 16 * 8;   // 589824 B
  if (ws_size >= need && d_ws != nullptr) {
    uint2* At = (uint2*)d_ws;
    prep_fused<<<72, 1024, 0, stream>>>(tensors, At);
    tn_fused<<<batch, NTH, 0, stream>>>(At, x, out);
  } else {
    tn_kernel_lds<<<batch, NTH, 0, stream>>>(tensors, x, out);
  }
}